// Round 1
// baseline (387.402 us; speedup 1.0000x reference)
//
#include <hip/hip_runtime.h>

#define PS 32
#define NPIX (PS * PS)
#define NB 36

// ---------------------------------------------------------------------------
// Init kernel: compute gk10[p] = float32(10 * CircularGaussKernel(32)) in f64,
// replicating numpy linspace + exp + normalize semantics, then cast to f32.
// ---------------------------------------------------------------------------
__global__ __launch_bounds__(256) void gk_init_kernel(float* __restrict__ gk10) {
    __shared__ double red[256];
    const int tid = threadIdx.x;
    const double delta = 32.0 / 31.0;       // numpy linspace step, f64
    const double sigma2 = 0.9 * 256.0;      // 0.9 * half^2, f64

    double kv[4];
    double s = 0.0;
#pragma unroll
    for (int j = 0; j < 4; ++j) {
        int p = tid * 4 + j;
        int r = p >> 5, c = p & 31;
        // numpy: y = arange(n)*delta + start; y[-1] = stop (exact endpoint)
        double xr = (r == 31) ? 16.0 : ((double)r * delta + (-16.0));
        double xc = (c == 31) ? 16.0 : ((double)c * delta + (-16.0));
        double d2 = xc * xc + xr * xr;       // xv^2 + yv^2 (xv = x[col])
        kv[j] = exp(-d2 / sigma2);
        s += kv[j];
    }
    red[tid] = s;
    __syncthreads();
    for (int off = 128; off > 0; off >>= 1) {
        if (tid < off) red[tid] += red[tid + off];
        __syncthreads();
    }
    double sum = red[0];
#pragma unroll
    for (int j = 0; j < 4; ++j) {
        int p = tid * 4 + j;
        // ref: gk_f32 = float32(k/sum); then 10.0 * gk_f32 in f32
        gk10[p] = __fmul_rn(10.0f, (float)(kv[j] / sum));
    }
}

// ---------------------------------------------------------------------------
// Main kernel: one block (256 threads) per 32x32 patch; 4 pixels per thread.
// ---------------------------------------------------------------------------
__global__ __launch_bounds__(256) void orient_kernel(const float* __restrict__ x,
                                                     const float* __restrict__ gk10,
                                                     float* __restrict__ out) {
    const float PI_F    = 3.14159265358979323846f;   // 0x40490FDB
    const float TWOPI_F = 6.28318530717958647692f;   // 0x40C90FDB

    __shared__ __align__(16) float tile[NPIX];
    __shared__ float hist[NB];
    __shared__ float smv[NB];

    const int tid = threadIdx.x;
    const int b = blockIdx.x;

    // Stage patch into LDS: 256 x float4 (coalesced, 4 KB)
    const float4* src = reinterpret_cast<const float4*>(x + (size_t)b * NPIX);
    reinterpret_cast<float4*>(tile)[tid] = src[tid];
    if (tid < NB) hist[tid] = 0.0f;
    __syncthreads();

    const int r  = tid >> 3;          // row 0..31 (8 threads per row)
    const int c0 = (tid & 7) << 2;    // col 0,4,...,28
    const int rowOff = r << 5;
    const int upOff  = ((r == 0)  ? 0  : (r - 1)) << 5;   // replicate pad
    const int dnOff  = ((r == 31) ? 31 : (r + 1)) << 5;

    float4 self = *reinterpret_cast<const float4*>(&tile[rowOff + c0]);
    float4 up   = *reinterpret_cast<const float4*>(&tile[upOff + c0]);
    float4 dn   = *reinterpret_cast<const float4*>(&tile[dnOff + c0]);
    float  lsc  = tile[rowOff + ((c0 == 0) ? 0 : (c0 - 1))];      // left edge (clamped)
    float  rsc  = tile[rowOff + ((c0 + 4 > 31) ? 31 : (c0 + 4))]; // right edge (clamped)
    float4 gkq  = *reinterpret_cast<const float4*>(&gk10[rowOff + c0]);

    float sv[4] = {self.x, self.y, self.z, self.w};
    float uv[4] = {up.x,   up.y,   up.z,   up.w};
    float dv[4] = {dn.x,   dn.y,   dn.z,   dn.w};
    float gk4[4] = {gkq.x, gkq.y, gkq.z, gkq.w};
    float lv[4] = {lsc,   sv[0], sv[1], sv[2]};
    float rv[4] = {sv[1], sv[2], sv[3], rsc};

#pragma unroll
    for (int j = 0; j < 4; ++j) {
        // Replicate reference f32 op order exactly (no contraction):
        float gx = __fmul_rn(0.5f, __fsub_rn(lv[j], rv[j]));   // 0.5*(left - right)
        float gy = __fmul_rn(0.5f, __fsub_rn(uv[j], dv[j]));   // 0.5*(up - down)
        float s2 = __fadd_rn(__fadd_rn(__fmul_rn(gx, gx), __fmul_rn(gy, gy)), 1e-10f);
        float mag = __fmul_rn(__fsqrt_rn(s2), gk4[j]);

        float ori  = atan2f(gy, gx);
        float obig = __fdiv_rn(__fmul_rn(36.0f, __fadd_rn(ori, PI_F)), TWOPI_F);
        float bo0f = floorf(obig);
        float wo1  = __fsub_rn(obig, bo0f);

        // Bin-boundary guard: if within 1e-5 of an integer, the ulp-level
        // accuracy of atan2f could flip floor(). Recompute via f64 atan2 ->
        // correctly-rounded f32. Rare (~2e-5 of pixels), so divergence is cheap.
        if (wo1 < 1e-5f || wo1 > 1.0f - 1e-5f) {
            ori  = (float)atan2((double)gy, (double)gx);
            obig = __fdiv_rn(__fmul_rn(36.0f, __fadd_rn(ori, PI_F)), TWOPI_F);
            bo0f = floorf(obig);
            wo1  = __fsub_rn(obig, bo0f);
        }

        int bo = (int)bo0f;              // in [0, 36]
        if (bo >= NB) bo -= NB;          // bo0 % 36
        float wo0 = __fmul_rn(__fsub_rn(1.0f, wo1), mag);
        atomicAdd(&hist[bo], wo0);
    }
    __syncthreads();

    // Angular smoothing: sm = 0.33*h[i-1] + 0.34*h[i] + 0.33*h[i+1], zero pad.
    if (tid < NB) {
        const float inv = 1.0f / 1024.0f;     // exact (power of 2)
        float hm = (tid > 0)      ? __fmul_rn(hist[tid - 1], inv) : 0.0f;
        float h0 =                  __fmul_rn(hist[tid],     inv);
        float hp = (tid < NB - 1) ? __fmul_rn(hist[tid + 1], inv) : 0.0f;
        smv[tid] = __fadd_rn(__fadd_rn(__fmul_rn(0.33f, hm), __fmul_rn(0.34f, h0)),
                             __fmul_rn(0.33f, hp));
    }
    __syncthreads();

    // First-wins argmax (matches jnp.argmax), then quantized angle.
    if (tid == 0) {
        float best = smv[0];
        int bi = 0;
#pragma unroll 1
        for (int i = 1; i < NB; ++i) {
            float v = smv[i];
            if (v > best) { best = v; bi = i; }
        }
        float t = __fdiv_rn(__fmul_rn(TWOPI_F, (float)bi), 36.0f);
        out[b] = __fsub_rn(PI_F, t);     // == -(t - pi), exact negation symmetry
    }
}

extern "C" void kernel_launch(void* const* d_in, const int* in_sizes, int n_in,
                              void* d_out, int out_size, void* d_ws, size_t ws_size,
                              hipStream_t stream) {
    const float* x = (const float*)d_in[0];
    float* out = (float*)d_out;
    float* gk10 = (float*)d_ws;   // 1024 floats = 4 KB scratch

    const int B = in_sizes[0] / NPIX;

    gk_init_kernel<<<1, 256, 0, stream>>>(gk10);
    orient_kernel<<<B, 256, 0, stream>>>(x, gk10, out);
}

// Round 2
// 373.220 us; speedup vs baseline: 1.0380x; 1.0380x over previous
//
#include <hip/hip_runtime.h>

#define PS 32
#define NPIX (PS * PS)
#define NB 36
#define WPB 4   // waves (patches) per block

// ---------------------------------------------------------------------------
// Init kernel: gk10[p] = float32(10 * CircularGaussKernel(32)) computed in f64,
// replicating numpy linspace + exp + normalize semantics, then cast to f32.
// ---------------------------------------------------------------------------
__global__ __launch_bounds__(256) void gk_init_kernel(float* __restrict__ gk10) {
    __shared__ double red[256];
    const int tid = threadIdx.x;
    const double delta = 32.0 / 31.0;       // numpy linspace step, f64
    const double sigma2 = 0.9 * 256.0;      // 0.9 * half^2, f64

    double kv[4];
    double s = 0.0;
#pragma unroll
    for (int j = 0; j < 4; ++j) {
        int p = tid * 4 + j;
        int r = p >> 5, c = p & 31;
        double xr = (r == 31) ? 16.0 : ((double)r * delta + (-16.0));
        double xc = (c == 31) ? 16.0 : ((double)c * delta + (-16.0));
        double d2 = xc * xc + xr * xr;
        kv[j] = exp(-d2 / sigma2);
        s += kv[j];
    }
    red[tid] = s;
    __syncthreads();
    for (int off = 128; off > 0; off >>= 1) {
        if (tid < off) red[tid] += red[tid + off];
        __syncthreads();
    }
    double sum = red[0];
#pragma unroll
    for (int j = 0; j < 4; ++j) {
        int p = tid * 4 + j;
        gk10[p] = __fmul_rn(10.0f, (float)(kv[j] / sum));
    }
}

// ---------------------------------------------------------------------------
// Main kernel: 4 waves per block, ONE WAVE PER PATCH. No __syncthreads.
// Each lane handles 16 pixels (4 float4 groups). Fast polynomial atan2
// computed directly in "bin units" with an f64-exact guard near boundaries.
// ---------------------------------------------------------------------------
__global__ __launch_bounds__(256) void orient_kernel(const float* __restrict__ x,
                                                     const float* __restrict__ gk10,
                                                     float* __restrict__ out) {
    const float PI_F    = 3.14159265358979323846f;   // 0x40490FDB
    const float TWOPI_F = 6.28318530717958647692f;   // 0x40C90FDB

    __shared__ __align__(16) float tile[WPB][NPIX];
    __shared__ float hist[WPB][NB];

    const int tid = threadIdx.x;
    const int w = tid >> 6;          // wave id within block
    const int l = tid & 63;          // lane within wave
    const int patch = blockIdx.x * WPB + w;

    float* tw = tile[w];
    float* hw = hist[w];

    // ---- Stage patch into LDS: 4 x float4 per lane, coalesced 1KB/wave-op
    const float4* src = reinterpret_cast<const float4*>(x + (size_t)patch * NPIX);
    float4* dst = reinterpret_cast<float4*>(tw);
#pragma unroll
    for (int k = 0; k < 4; ++k) {
        dst[k * 64 + l] = src[k * 64 + l];
    }
    if (l < NB) hw[l] = 0.0f;
    // ds_writes complete before any lane reads other lanes' data (same wave,
    // lockstep exec; the memory clobber stops compiler reordering)
    asm volatile("s_waitcnt lgkmcnt(0)" ::: "memory");

    // ---- Per-pixel gradient -> bin -> histogram (16 px/lane, 4 groups of 4)
#pragma unroll
    for (int k = 0; k < 4; ++k) {
        const int g  = k * 64 + l;        // float4 group 0..255
        const int r  = g >> 3;            // row 0..31
        const int c0 = (g & 7) << 2;      // col 0,4,...,28
        const int rowOff = r << 5;
        const int upOff  = ((r == 0)  ? 0  : (r - 1)) << 5;   // replicate pad
        const int dnOff  = ((r == 31) ? 31 : (r + 1)) << 5;

        float4 self = *reinterpret_cast<const float4*>(&tw[rowOff + c0]);
        float4 up   = *reinterpret_cast<const float4*>(&tw[upOff + c0]);
        float4 dn   = *reinterpret_cast<const float4*>(&tw[dnOff + c0]);
        float  lsc  = tw[rowOff + ((c0 == 0) ? 0 : (c0 - 1))];
        float  rsc  = tw[rowOff + ((c0 + 4 > 31) ? 31 : (c0 + 4))];
        float4 gkq  = *reinterpret_cast<const float4*>(&gk10[rowOff + c0]);

        float sv[4]  = {self.x, self.y, self.z, self.w};
        float uv[4]  = {up.x,   up.y,   up.z,   up.w};
        float dv[4]  = {dn.x,   dn.y,   dn.z,   dn.w};
        float gk4[4] = {gkq.x,  gkq.y,  gkq.z,  gkq.w};
        float lv[4]  = {lsc,   sv[0], sv[1], sv[2]};
        float rv[4]  = {sv[1], sv[2], sv[3], rsc};

#pragma unroll
        for (int j = 0; j < 4; ++j) {
            // Reference f32 op order for the magnitude path (no contraction):
            float gx = __fmul_rn(0.5f, __fsub_rn(lv[j], rv[j]));
            float gy = __fmul_rn(0.5f, __fsub_rn(uv[j], dv[j]));
            float s2 = __fadd_rn(__fadd_rn(__fmul_rn(gx, gx), __fmul_rn(gy, gy)), 1e-10f);
            float mag = __fmul_rn(__fsqrt_rn(s2), gk4[j]);

            // ---- Fast atan2 directly in bin units: obig = (atan2+pi)*36/(2pi)
            // pi/2 -> 9 bins, pi -> 18 bins (exact integers).
            float ax = fabsf(gx), ay = fabsf(gy);
            float mn = fminf(ax, ay), mx = fmaxf(ax, ay);
            float rr = mn * __builtin_amdgcn_rcpf(mx);   // ~1 ulp
            float t  = rr * rr;
            // SLEEF atanf minimax poly (deg 17 odd), |err| ~3.5 ulp on [0,1]
            float u = 0.00282363896258175373077393f;
            u = fmaf(u, t, -0.0159569028764963150024414f);
            u = fmaf(u, t,  0.0425049886107444763183594f);
            u = fmaf(u, t, -0.0748900920152664184570312f);
            u = fmaf(u, t,  0.106347933411598205566406f);
            u = fmaf(u, t, -0.142027363181114196777344f);
            u = fmaf(u, t,  0.199926957488059997558594f);
            u = fmaf(u, t, -0.333331018686294555664062f);
            float at = fmaf(rr * t, u, rr);              // atan(rr) in [0, pi/4]
            float A  = at * 5.72957795130823208768f;     // -> bin units [0, 4.5]
            A = (mx > 0.0f) ? A : 0.0f;                  // atan2(0,0) = 0
            float q = (ay > ax) ? (9.0f - A) : A;        // [0, 9]
            q = (gx < 0.0f) ? (18.0f - q) : q;           // [0, 18]
            q = (gy < 0.0f) ? (0.0f - q) : q;            // [-18, 18]
            float obig = q + 18.0f;                      // [0, 36]
            float bo0f = floorf(obig);
            float wo1  = __fsub_rn(obig, bo0f);

            // Boundary guard: our obig error <= ~5e-6 bin units; if within
            // 2e-5 of an integer, recompute exactly via f64 atan2 so the
            // floor() decision matches the reference bitwise.
            if (wo1 < 2e-5f || wo1 > 1.0f - 2e-5f) {
                float ori = (float)atan2((double)gy, (double)gx);
                obig = __fdiv_rn(__fmul_rn(36.0f, __fadd_rn(ori, PI_F)), TWOPI_F);
                bo0f = floorf(obig);
                wo1  = __fsub_rn(obig, bo0f);
            }

            int bo = (int)bo0f;            // in [0, 36]
            if (bo >= NB) bo -= NB;        // % 36
            float wo0 = __fmul_rn(__fsub_rn(1.0f, wo1), mag);
            atomicAdd(&hw[bo], wo0);
        }
    }
    // all 64 lanes' ds_add_f32 complete before reading hist
    asm volatile("s_waitcnt lgkmcnt(0)" ::: "memory");

    // ---- Smoothing (lanes 0..35): sm = 0.33*h[i-1] + 0.34*h[i] + 0.33*h[i+1]
    float sm = 0.0f;
    if (l < NB) {
        const float inv = 1.0f / 1024.0f;  // exact power of 2
        float hm = (l > 0)      ? __fmul_rn(hw[l - 1], inv) : 0.0f;
        float h0 =                __fmul_rn(hw[l],     inv);
        float hp = (l < NB - 1) ? __fmul_rn(hw[l + 1], inv) : 0.0f;
        sm = __fadd_rn(__fadd_rn(__fmul_rn(0.33f, hm), __fmul_rn(0.34f, h0)),
                       __fmul_rn(0.33f, hp));
    }

    // ---- First-wins argmax via packed-key butterfly reduce.
    // sm >= 0 always (weights and mag are positive), so IEEE bits are
    // monotonic; tie -> larger (63-l) -> smaller l (matches jnp.argmax).
    unsigned long long key =
        (l < NB) ? ((((unsigned long long)__float_as_uint(sm)) << 6) |
                    (unsigned long long)(63 - l))
                 : 0ull;
#pragma unroll
    for (int off = 32; off > 0; off >>= 1) {
        unsigned long long o = __shfl_xor(key, off, 64);
        key = (o > key) ? o : key;
    }

    if (l == 0) {
        int bi = 63 - (int)(key & 63);
        float t2 = __fdiv_rn(__fmul_rn(TWOPI_F, (float)bi), 36.0f);
        out[patch] = __fsub_rn(PI_F, t2);
    }
}

extern "C" void kernel_launch(void* const* d_in, const int* in_sizes, int n_in,
                              void* d_out, int out_size, void* d_ws, size_t ws_size,
                              hipStream_t stream) {
    const float* x = (const float*)d_in[0];
    float* out = (float*)d_out;
    float* gk10 = (float*)d_ws;   // 1024 floats = 4 KB scratch

    const int B = in_sizes[0] / NPIX;

    gk_init_kernel<<<1, 256, 0, stream>>>(gk10);
    orient_kernel<<<B / WPB, 256, 0, stream>>>(x, gk10, out);
}